// Round 2
// baseline (148.809 us; speedup 1.0000x reference)
//
#include <hip/hip_runtime.h>
#include <cstddef>

#define TDIM 1024
#define SEQ 8192
#define NROWS 4096

// --- Phase 0: histogram of his over [0,1024). One block, no global atomics, no memset. ---
__global__ __launch_bounds__(1024) void hist_kernel(const int* __restrict__ his,
                                                    int* __restrict__ counts) {
    __shared__ int lc[TDIM];
    const int tid = threadIdx.x;
    lc[tid] = 0;
    __syncthreads();
#pragma unroll
    for (int k = 0; k < 8; ++k)
        atomicAdd(&lc[his[tid + 1024 * k]], 1);
    __syncthreads();
    counts[tid] = lc[tid];
}

// --- Phase A: P[r][t] = softmax weight for table row r, masked/weighted by counts.
//     1024 blocks (one per r) x 256 threads. Output: 4 MB table in ws. ---
__global__ __launch_bounds__(256) void table_kernel(const float* __restrict__ M,
                                                    const int* __restrict__ counts,
                                                    float* __restrict__ P) {
    __shared__ float red[16];
    const int tid = threadIdx.x;
    const int r = blockIdx.x;
    const float* Mrow = M + (size_t)r * TDIM;

    float m[4];
    int   c[4];
#pragma unroll
    for (int k = 0; k < 4; ++k) {
        int t = tid + 256 * k;
        m[k] = Mrow[t];
        c[k] = counts[t];
    }

    // masked block max (only columns present in his participate)
    float lmax = -3.402823466e38f;
#pragma unroll
    for (int k = 0; k < 4; ++k)
        if (c[k] > 0) lmax = fmaxf(lmax, m[k]);
#pragma unroll
    for (int off = 32; off > 0; off >>= 1)
        lmax = fmaxf(lmax, __shfl_down(lmax, off, 64));
    const int wave = tid >> 6, lane = tid & 63;
    if (lane == 0) red[wave] = lmax;
    __syncthreads();
    if (tid == 0) {
        float g = fmaxf(fmaxf(red[0], red[1]), fmaxf(red[2], red[3]));
        red[8] = g;
    }
    __syncthreads();
    const float gmax = red[8];

    // histogram-weighted exp sum: sum_t c[t] * exp(M[r][t] - max)
    float e[4];
    float lsum = 0.f;
#pragma unroll
    for (int k = 0; k < 4; ++k) {
        e[k] = __expf(m[k] - gmax);
        lsum += (float)c[k] * e[k];
    }
#pragma unroll
    for (int off = 32; off > 0; off >>= 1)
        lsum += __shfl_down(lsum, off, 64);
    if (lane == 0) red[4 + wave] = lsum;
    __syncthreads();
    if (tid == 0) red[9] = 1.0f / (red[4] + red[5] + red[6] + red[7]);
    __syncthreads();
    const float inv = red[9];

    float* Prow = P + (size_t)r * TDIM;
#pragma unroll
    for (int k = 0; k < 4; ++k)
        Prow[tid + 256 * k] = e[k] * inv;   // entries with c==0 are never gathered
}

// --- Phase B: out[i][j] = P[cur[i]][his[j]]. 2 rows per block; interleaved float2
//     LDS table so one ds_read_b64 serves both rows. Coalesced float4 stores. ---
__global__ __launch_bounds__(256) void gather_kernel(const int* __restrict__ his,
                                                     const int* __restrict__ cur,
                                                     const float* __restrict__ P,
                                                     float* __restrict__ out) {
    __shared__ float2 probs2[TDIM];
    const int tid = threadIdx.x;
    const int row0 = blockIdx.x * 2;
    const int r0 = cur[row0];
    const int r1 = cur[row0 + 1];

    // stage interleaved prob table: probs2[t] = { P[r0][t], P[r1][t] }
    const float4* P0 = (const float4*)(P + (size_t)r0 * TDIM);
    const float4* P1 = (const float4*)(P + (size_t)r1 * TDIM);
    float4 a = P0[tid];
    float4 b = P1[tid];
    probs2[4 * tid + 0] = make_float2(a.x, b.x);
    probs2[4 * tid + 1] = make_float2(a.y, b.y);
    probs2[4 * tid + 2] = make_float2(a.z, b.z);
    probs2[4 * tid + 3] = make_float2(a.w, b.w);
    __syncthreads();

    const int4* his4 = (const int4*)his;                 // 2048 int4
    float4* out0 = (float4*)(out + (size_t)row0 * SEQ);
    float4* out1 = (float4*)(out + (size_t)(row0 + 1) * SEQ);
#pragma unroll
    for (int it = 0; it < 8; ++it) {
        int j4 = it * 256 + tid;
        int4 h = his4[j4];
        float2 px = probs2[h.x];
        float2 py = probs2[h.y];
        float2 pz = probs2[h.z];
        float2 pw = probs2[h.w];
        float4 o0 = make_float4(px.x, py.x, pz.x, pw.x);
        float4 o1 = make_float4(px.y, py.y, pz.y, pw.y);
        out0[j4] = o0;
        out1[j4] = o1;
    }
}

extern "C" void kernel_launch(void* const* d_in, const int* in_sizes, int n_in,
                              void* d_out, int out_size, void* d_ws, size_t ws_size,
                              hipStream_t stream) {
    const int*   his = (const int*)d_in[0];    // (8192,) int32 in [0,1024)
    const int*   cur = (const int*)d_in[1];    // (4096,) int32 in [0,1024)
    const float* M   = (const float*)d_in[2];  // (1024,1024) fp32
    float* out = (float*)d_out;                // (4096,8192) fp32

    float* P      = (float*)d_ws;                                  // 4 MB
    int*   counts = (int*)((char*)d_ws + (size_t)TDIM * TDIM * 4); // 4 KB

    hist_kernel<<<1, 1024, 0, stream>>>(his, counts);
    table_kernel<<<TDIM, 256, 0, stream>>>(M, counts, P);
    gather_kernel<<<NROWS / 2, 256, 0, stream>>>(his, cur, P, out);
}